// Round 19
// baseline (8228.680 us; speedup 1.0000x reference)
//
#include <hip/hip_runtime.h>

typedef __bf16 bf16x8 __attribute__((ext_vector_type(8)));
typedef float f32x4 __attribute__((ext_vector_type(4)));
typedef unsigned short u16;
typedef unsigned long long u64;

#define NSTEP 512
#define WLDS_BYTES 147456   // [32 kk][64 rb][36] u16

#define AL(p)   __hip_atomic_load((p), __ATOMIC_RELAXED, __HIP_MEMORY_SCOPE_AGENT)
#define AS(p,v) __hip_atomic_store((p), (v), __ATOMIC_RELAXED, __HIP_MEMORY_SCOPE_AGENT)

__device__ __forceinline__ u16 f2bf(float f) {
  union { float f; unsigned u; } x; x.f = f;
  return (u16)((x.u + 0x7fffu + ((x.u >> 16) & 1u)) >> 16);
}

// zero h buffer 0 + 512 per-wave epoch flags
__global__ void prep_kernel(u64* __restrict__ H0, int* __restrict__ F) {
  int i = blockIdx.x * blockDim.x + threadIdx.x;
  if (i < 16384) AS(H0 + i, 0ULL);
  if (i < 16384) AS(&F[i], 0);
}

// A1[t*64+b][512] bf16 embedding gather
__global__ void gather_kernel(const int* __restrict__ sent, const float* __restrict__ emb,
                              u16* __restrict__ A1) {
  int row = blockIdx.x * 4 + (threadIdx.x >> 6);   // t*64+b
  int lane = threadIdx.x & 63;
  int t = row >> 6, b = row & 63;
  int idx = sent[b * 512 + t];
  const float* src = emb + (size_t)idx * 512 + lane * 8;
  u16* dst = A1 + (size_t)row * 512 + lane * 8;
  #pragma unroll
  for (int k = 0; k < 8; ++k) dst[k] = f2bf(src[k]);
}

// 64 WGs x 512 thr (fat WGs). WG j owns h cols [j*16, j*16+16); gate-row packing
// rb = c*4 + g (weight row = g*1024 + j*16 + c); gates adjacent in lanes ->
// shfl_xor(1/2/3) combine. Wave w8 = bt*2+cw: batch rows bt*16..+16, col-half
// cw*8..+8 (2 MFMA n-tiles). Weights: x(K=512)+h-K[0,512) in 144KB LDS;
// h-K[512,1024) in 128 VGPRs. h exchange: r15 dataflow (per-step fresh buffers,
// sc1 stores, cached fills, per-wave epoch flags) — ONE wait round: lane l
// polls producer WG l's two bt-matched wave flags.
__global__ void __launch_bounds__(512, 1)
lstm_kernel(const u16* __restrict__ A1,
            const float* __restrict__ wih, const float* __restrict__ whh,
            const float* __restrict__ bih, const float* __restrict__ bhh,
            u16* __restrict__ H, float* __restrict__ out, int* __restrict__ F) {
  extern __shared__ u16 wlds[];             // [32][64][36] = 147456 B
  __shared__ alignas(16) u16 hx[64][16];    // h packing bounce (2 KB)

  const int j   = blockIdx.x;          // 0..63
  const int tid = threadIdx.x;
  const int w8  = tid >> 6;            // 0..7
  const int bt  = w8 >> 1;             // batch tile 0..3
  const int cw  = w8 & 1;              // col-half 0..1
  const int l   = tid & 63;
  const int lr  = l & 15, lk = l >> 4;
  const int g   = lr & 3, cc = lr >> 2;

  // ---- stage LDS weights: kk 0..15 = w_ih (K=512), kk 16..31 = w_hh K[0,512) ----
  for (int task = tid; task < 8192; task += 512) {
    int kk = task >> 8;                 // 0..31
    int rem = task & 255;
    int rb = rem >> 2, q = rem & 3;     // rb = c*4+g
    int row = (rb & 3) * 1024 + j * 16 + (rb >> 2);
    const float* src = (kk < 16) ? (wih + (size_t)row * 512 + kk * 32 + q * 8)
                                 : (whh + (size_t)row * 1024 + (kk - 16) * 32 + q * 8);
    u16* dst = wlds + (size_t)(kk * 64 + rb) * 36 + q * 8;
    #pragma unroll
    for (int e = 0; e < 8; ++e) dst[e] = f2bf(src[e]);
  }

  // ---- register weights: w_hh K[512,1024) for this wave's 2 n-tiles ----
  const int col0 = cw * 8 + cc;              // within-16 col (tile0); tile1 = +4
  const int r0 = g * 1024 + j * 16 + col0;
  const int r1 = r0 + 4;
  bf16x8 wv0[16], wv1[16];
  {
    const float* p0 = whh + (size_t)r0 * 1024 + 512 + lk * 8;
    const float* p1 = whh + (size_t)r1 * 1024 + 512 + lk * 8;
    #pragma unroll
    for (int c = 0; c < 16; ++c) {
      union { bf16x8 v; u16 s[8]; } u0, u1;
      #pragma unroll
      for (int e = 0; e < 8; ++e) { u0.s[e] = f2bf(p0[c * 32 + e]); u1.s[e] = f2bf(p1[c * 32 + e]); }
      wv0[c] = u0.v; wv1[c] = u1.v;
    }
  }
  __syncthreads();

  const float bias0 = bih[r0] + bhh[r0];
  const float bias1 = bih[r1] + bhh[r1];
  const float sca = (g == 2) ? 2.f : 1.f;    // tanh-as-sigmoid for gate g~
  const float bd  = (g == 2) ? -1.f : 0.f;
  const int arow = bt * 16 + lr;             // batch row for A fragments
  const u16* bxp = wlds + (size_t)(cw * 32 + lr) * 36 + lk * 8;  // +kk*2304; tile1 +576

  float cst0[4] = {0,0,0,0}, cst1[4] = {0,0,0,0};
  bf16x8 ha[8], hb[8];

#define LD8A(BUF, C0)                                                       \
  { _Pragma("unroll")                                                       \
    for (int r = 0; r < 8; ++r) BUF[r] = *(const bf16x8*)(ap + ((C0) + r) * 32); }
#define LD8H(BUF, C0)                                                       \
  { _Pragma("unroll")                                                       \
    for (int r = 0; r < 8; ++r) BUF[r] = *(const bf16x8*)(hp + ((C0) + r) * 32); }
#define MM8L(PA, PB, BUF, KK0)                                              \
  { _Pragma("unroll")                                                       \
    for (int r = 0; r < 8; ++r) {                                           \
      bf16x8 b0 = *(const bf16x8*)(bxp + (size_t)((KK0) + r) * 2304);       \
      bf16x8 b1 = *(const bf16x8*)(bxp + (size_t)((KK0) + r) * 2304 + 576); \
      PA = __builtin_amdgcn_mfma_f32_16x16x32_bf16(BUF[r], b0, PA, 0, 0, 0); \
      PB = __builtin_amdgcn_mfma_f32_16x16x32_bf16(BUF[r], b1, PB, 0, 0, 0); \
    } }
#define MM8R(PA, PB, BUF, V0)                                               \
  { _Pragma("unroll")                                                       \
    for (int r = 0; r < 8; ++r) {                                           \
      PA = __builtin_amdgcn_mfma_f32_16x16x32_bf16(BUF[r], wv0[(V0) + r], PA, 0, 0, 0); \
      PB = __builtin_amdgcn_mfma_f32_16x16x32_bf16(BUF[r], wv1[(V0) + r], PB, 0, 0, 0); \
    } }

  #pragma unroll 1
  for (int t = 0; t < NSTEP; ++t) {
    // flag loads issue first: lane l covers producer WG l, waves (bt,0) & (bt,1)
    int v0 = AL(F + (l * 8 + bt * 2 + 0) * 32);
    int v1 = AL(F + (l * 8 + bt * 2 + 1) * 32);
    // x-projection (K=512): A1 cached loads + LDS B, covers the flag RT
    const u16* ap = A1 + ((size_t)t * 64 + arow) * 512 + lk * 8;
    f32x4 p0a = { bias0, bias0, bias0, bias0 };
    f32x4 p1a = { bias1, bias1, bias1, bias1 };
    f32x4 p0b = { 0.f, 0.f, 0.f, 0.f };
    f32x4 p1b = { 0.f, 0.f, 0.f, 0.f };
    LD8A(ha, 0); LD8A(hb, 8);
    MM8L(p0a, p1a, ha, 0);
    MM8L(p0b, p1b, hb, 8);
    // one wait round for all h producers of this batch tile
    while (v0 < t) { __builtin_amdgcn_s_sleep(1); v0 = AL(F + (l * 8 + bt * 2 + 0) * 32); }
    while (v1 < t) { __builtin_amdgcn_s_sleep(1); v1 = AL(F + (l * 8 + bt * 2 + 1) * 32); }
    // h-projection (K=1024): cached fills, double-buffered
    const u16* hp = H + (size_t)t * 65536 + (size_t)arow * 1024 + lk * 8;
    LD8H(ha, 0); LD8H(hb, 8);
    MM8L(p0a, p1a, ha, 16);      // h-K [0,256)   (LDS kk 16..23)
    LD8H(ha, 16);
    MM8L(p0b, p1b, hb, 24);      // h-K [256,512) (LDS kk 24..31)
    LD8H(hb, 24);
    MM8R(p0a, p1a, ha, 0);       // h-K [512,768)  (regs)
    MM8R(p0b, p1b, hb, 8);       // h-K [768,1024) (regs)

    // activations: gates adjacent in lanes (g = lr&3) -> xor 1/2/3
    float hv0[4], cn0[4], hv1[4], cn1[4];
    #pragma unroll
    for (int r = 0; r < 4; ++r) {
      float x0 = p0a[r] + p0b[r];
      float x1 = p1a[r] + p1b[r];
      float a0 = sca / (1.f + __expf(-sca * x0)) + bd;
      float a1 = sca / (1.f + __expf(-sca * x1)) + bd;
      float f0 = __shfl_xor(a0, 1), g0 = __shfl_xor(a0, 2), o0 = __shfl_xor(a0, 3);
      float f1 = __shfl_xor(a1, 1), g1 = __shfl_xor(a1, 2), o1 = __shfl_xor(a1, 3);
      float c0 = f0 * cst0[r] + a0 * g0;   // valid at g==0 lanes (a = i there)
      float c1 = f1 * cst1[r] + a1 * g1;
      cst0[r] = c0; cst1[r] = c1;
      hv0[r] = o0 * (2.f / (1.f + __expf(-2.f * c0)) - 1.f);  cn0[r] = c0;
      hv1[r] = o1 * (2.f / (1.f + __expf(-2.f * c1)) - 1.f);  cn1[r] = c1;
    }

    if (t == NSTEP - 1) {
      if (g == 0) {
        #pragma unroll
        for (int r = 0; r < 4; ++r) {
          int R = bt * 16 + lk * 4 + r;
          int C = j * 16 + col0;
          out[(size_t)R * 1024 + C]              = hv0[r];
          out[65536 + (size_t)R * 1024 + C]      = hv0[r];
          out[131072 + (size_t)R * 1024 + C]     = cn0[r];
          out[(size_t)R * 1024 + C + 4]          = hv1[r];
          out[65536 + (size_t)R * 1024 + C + 4]  = hv1[r];
          out[131072 + (size_t)R * 1024 + C + 4] = cn1[r];
        }
      }
    } else {
      // pack this wave's 16 rows x 8 cols into hx (same-wave ds order; no barrier)
      if (g == 0) {
        #pragma unroll
        for (int r = 0; r < 4; ++r) {
          hx[bt * 16 + lk * 4 + r][cw * 8 + cc]     = f2bf(hv0[r]);
          hx[bt * 16 + lk * 4 + r][cw * 8 + cc + 4] = f2bf(hv1[r]);
        }
      }
      if (l < 16) {   // one 16B row-half per lane -> 2 agent-scope u64 stores
        const u64* s = (const u64*)(&hx[bt * 16 + l][cw * 8]);
        u64* hw = (u64*)(H + (size_t)(t + 1) * 65536
                           + (size_t)(bt * 16 + l) * 1024 + j * 16 + cw * 8);
        AS(hw, s[0]); AS(hw + 1, s[1]);
      }
      // this wave's h stores reach the coherence point, then publish its flag
      asm volatile("s_waitcnt vmcnt(0)" ::: "memory");
      if (l == 0) AS(F + (j * 8 + w8) * 32, t + 1);
    }
  }
#undef LD8A
#undef LD8H
#undef MM8L
#undef MM8R
}

extern "C" void kernel_launch(void* const* d_in, const int* in_sizes, int n_in,
                              void* d_out, int out_size, void* d_ws, size_t ws_size,
                              hipStream_t stream) {
  const int*   sent = (const int*)d_in[0];
  const float* emb  = (const float*)d_in[1];
  const float* w_ih = (const float*)d_in[2];
  const float* w_hh = (const float*)d_in[3];
  const float* b_ih = (const float*)d_in[4];
  const float* b_hh = (const float*)d_in[5];
  float* out = (float*)d_out;

  // A1 32Mi | H 512 x 128Ki = 64Mi | F 64Ki  (~96.1 MiB; r15-proven available)
  char* ws = (char*)d_ws;
  u16* A1 = (u16*)ws;
  u16* H  = (u16*)(ws + 33554432);
  int* F  = (int*)(ws + 33554432 + 67108864);

  prep_kernel<<<256, 256, 0, stream>>>((u64*)H, F);
  gather_kernel<<<8192, 256, 0, stream>>>(sent, emb, A1);

  (void)hipFuncSetAttribute((const void*)lstm_kernel,
                            hipFuncAttributeMaxDynamicSharedMemorySize, WLDS_BYTES);

  void* args[] = { (void*)&A1, (void*)&w_ih, (void*)&w_hh,
                   (void*)&b_ih, (void*)&b_hh, (void*)&H, (void*)&out, (void*)&F };
  hipError_t err = hipLaunchCooperativeKernel((void*)lstm_kernel, dim3(64), dim3(512),
                                              args, WLDS_BYTES, stream);
  if (err != hipSuccess) {
    // dataflow kernel needs co-residency only; 64 WGs at 1 block/CU trivially fit
    lstm_kernel<<<dim3(64), dim3(512), WLDS_BYTES, stream>>>(A1, w_ih, w_hh,
                                                             b_ih, b_hh, H, out, F);
  }
}

// Round 20
// 6940.308 us; speedup vs baseline: 1.1856x; 1.1856x over previous
//
#include <hip/hip_runtime.h>

typedef __bf16 bf16x8 __attribute__((ext_vector_type(8)));
typedef float f32x4 __attribute__((ext_vector_type(4)));
typedef unsigned short u16;
typedef unsigned long long u64;

#define NSTEP 512
#define WLDS_BYTES 110592   // [48 kk][2 nt][16 rb][36] u16

#define AL(p)   __hip_atomic_load((p), __ATOMIC_RELAXED, __HIP_MEMORY_SCOPE_AGENT)
#define AS(p,v) __hip_atomic_store((p), (v), __ATOMIC_RELAXED, __HIP_MEMORY_SCOPE_AGENT)

__device__ __forceinline__ u16 f2bf(float f) {
  union { float f; unsigned u; } x; x.f = f;
  return (u16)((x.u + 0x7fffu + ((x.u >> 16) & 1u)) >> 16);
}

// zero h buffer 0 + 512 per-wave epoch flags
__global__ void prep_kernel(u64* __restrict__ H0, int* __restrict__ F) {
  int i = blockIdx.x * blockDim.x + threadIdx.x;
  if (i < 16384) AS(H0 + i, 0ULL);
  if (i < 16384) AS(&F[i], 0);
}

// A1[t*64+b][512] bf16 embedding gather
__global__ void gather_kernel(const int* __restrict__ sent, const float* __restrict__ emb,
                              u16* __restrict__ A1) {
  int row = blockIdx.x * 4 + (threadIdx.x >> 6);   // t*64+b
  int lane = threadIdx.x & 63;
  int t = row >> 6, b = row & 63;
  int idx = sent[b * 512 + t];
  const float* src = emb + (size_t)idx * 512 + lane * 8;
  u16* dst = A1 + (size_t)row * 512 + lane * 8;
  #pragma unroll
  for (int k = 0; k < 8; ++k) dst[k] = f2bf(src[k]);
}

// 128 WGs x 256 thr. WG jc owns h cols [jc*8, jc*8+8) as 2 n-tiles; gate packing
// per tile rb = g*4+nn = lr (weight row = g*1024 + jc*8 + nt*4 + nn).
// Wave w = batch tile (rows w*16..+16), computes BOTH n-tiles (96 MFMAs/step).
// Weights in 108KB padded dynamic LDS (r13-proven). h exchange: r15/r18 dataflow
// (per-step fresh buffers, sc1 stores, cached fills, per-wave epoch flags).
// 512 actors; TWO wait rounds: lane l polls producer WGs l and 64+l (wave w).
__global__ void __launch_bounds__(256, 1)
lstm_kernel(const u16* __restrict__ A1,
            const float* __restrict__ wih, const float* __restrict__ whh,
            const float* __restrict__ bih, const float* __restrict__ bhh,
            u16* __restrict__ H, float* __restrict__ out, int* __restrict__ F) {
  extern __shared__ u16 wlds[];             // [48][2][16][36] u16 = 110592 B
  __shared__ alignas(16) u16 hx[4][16][8];  // per-wave h-store packing bounce

  const int jc  = blockIdx.x;          // 0..127
  const int tid = threadIdx.x;
  const int w   = tid >> 6;            // wave = batch tile 0..3
  const int l   = tid & 63;
  const int lr  = l & 15, lk = l >> 4;
  const int g   = lr >> 2, nn = lr & 3;

  // ---- stage weights fp32->bf16 into padded dynamic LDS (once) ----
  for (int task = tid; task < 6144; task += 256) {
    int kk = task >> 7;                 // K chunk of 32 (0..47)
    int rem = task & 127;
    int ntt = rem >> 6;
    int rem2 = rem & 63;
    int rb = rem2 >> 2, q = rem2 & 3;
    int row = (rb >> 2) * 1024 + jc * 8 + ntt * 4 + (rb & 3);
    const float* src = (kk < 16) ? (wih + (size_t)row * 512 + kk * 32 + q * 8)
                                 : (whh + (size_t)row * 1024 + (kk - 16) * 32 + q * 8);
    u16* dst = wlds + (size_t)((kk * 2 + ntt) * 16 + rb) * 36 + q * 8;
    #pragma unroll
    for (int e = 0; e < 8; ++e) dst[e] = f2bf(src[e]);
  }
  __syncthreads();

  const int wr0 = g * 1024 + jc * 8 + nn;        // tile0 gate row
  const int wr1 = wr0 + 4;                       // tile1
  const float bias0 = bih[wr0] + bhh[wr0];
  const float bias1 = bih[wr1] + bhh[wr1];
  const float sca = (g == 2) ? 2.f : 1.f;        // tanh-as-sigmoid scaling
  const float bd  = (g == 2) ? -1.f : 0.f;
  const int arow = w * 16 + lr;                  // batch row for A fragments
  const u16* bxp = wlds + (size_t)lr * 36 + lk * 8;  // +kk*1152; tile1 +576

  float cst0[4] = {0,0,0,0}, cst1[4] = {0,0,0,0};

  // prefetch A1 fragments for t=0
  bf16x8 ax[16];
  {
    const u16* apre = A1 + (size_t)arow * 512 + lk * 8;
    #pragma unroll
    for (int kk = 0; kk < 16; ++kk) ax[kk] = *(const bf16x8*)(apre + kk * 32);
  }

  bf16x8 ha[8], hb[8];

#define WAITV(vv, P0)                                                       \
  { while (vv < t) { __builtin_amdgcn_s_sleep(1);                           \
                     vv = AL(F + (((P0) + l) * 4 + w) * 32); } }
#define LD8(BUF, CH)                                                        \
  { _Pragma("unroll")                                                       \
    for (int r = 0; r < 8; ++r)                                             \
      BUF[r] = *(const bf16x8*)(hp + (CH) * 256 + r * 32); }
#define MMX(KK)                                                             \
  { bf16x8 b0 = *(const bf16x8*)(bxp + (size_t)(KK) * 1152);                \
    bf16x8 b1 = *(const bf16x8*)(bxp + (size_t)(KK) * 1152 + 576);          \
    acx0 = __builtin_amdgcn_mfma_f32_16x16x32_bf16(ax[KK], b0, acx0, 0, 0, 0); \
    acx1 = __builtin_amdgcn_mfma_f32_16x16x32_bf16(ax[KK], b1, acx1, 0, 0, 0); }
#define MMH(BUF, KK0)                                                       \
  { _Pragma("unroll")                                                       \
    for (int r = 0; r < 8; ++r) {                                           \
      bf16x8 b0 = *(const bf16x8*)(bxp + (size_t)((KK0) + r) * 1152);       \
      bf16x8 b1 = *(const bf16x8*)(bxp + (size_t)((KK0) + r) * 1152 + 576); \
      ac0 = __builtin_amdgcn_mfma_f32_16x16x32_bf16(BUF[r], b0, ac0, 0, 0, 0); \
      ac1 = __builtin_amdgcn_mfma_f32_16x16x32_bf16(BUF[r], b1, ac1, 0, 0, 0); \
    } }

  #pragma unroll 1
  for (int t = 0; t < NSTEP; ++t) {
    // issue both wait-round flag loads concurrently (r16)
    int v0 = AL(F + ((l)       * 4 + w) * 32);   // producer WGs 0..63  -> chunks 0,1
    int v1 = AL(F + ((64 + l)  * 4 + w) * 32);   // producer WGs 64..127 -> chunks 2,3
    // x-proj first half covers the flag RT
    f32x4 acx0 = { bias0, bias0, bias0, bias0 };
    f32x4 acx1 = { bias1, bias1, bias1, bias1 };
    #pragma unroll
    for (int kk = 0; kk < 8; ++kk) MMX(kk);
    // detect round A + issue chunk 0/1 fills
    const u16* hp = H + (size_t)t * 65536 + (size_t)arow * 1024 + lk * 8;
    WAITV(v0, 0);
    LD8(ha, 0);
    LD8(hb, 1);
    // x-proj second half covers the fills
    #pragma unroll
    for (int kk = 8; kk < 16; ++kk) MMX(kk);
    // h-projection (K=1024), 2 independent chains per tile via ac/acx
    f32x4 ac0 = { 0.f, 0.f, 0.f, 0.f };
    f32x4 ac1 = { 0.f, 0.f, 0.f, 0.f };
    MMH(ha, 16);
    WAITV(v1, 64);
    LD8(ha, 2);
    MMH(hb, 24);
    LD8(hb, 3);
    MMH(ha, 32);
    MMH(hb, 40);

    // activations: gates at shfl_xor 4/8/12 (rb = g*4+nn); lanes g==0 own cols
    float hv0[4], cn0[4], hv1[4], cn1[4];
    #pragma unroll
    for (int r = 0; r < 4; ++r) {
      float x0 = acx0[r] + ac0[r];
      float x1 = acx1[r] + ac1[r];
      float a0 = sca / (1.f + __expf(-sca * x0)) + bd;
      float a1 = sca / (1.f + __expf(-sca * x1)) + bd;
      float f0 = __shfl_xor(a0, 4), g0 = __shfl_xor(a0, 8), o0 = __shfl_xor(a0, 12);
      float f1 = __shfl_xor(a1, 4), g1 = __shfl_xor(a1, 8), o1 = __shfl_xor(a1, 12);
      float c0 = f0 * cst0[r] + a0 * g0;   // a = i at lanes lr<4
      float c1 = f1 * cst1[r] + a1 * g1;
      cst0[r] = c0; cst1[r] = c1;
      hv0[r] = o0 * (2.f / (1.f + __expf(-2.f * c0)) - 1.f);  cn0[r] = c0;
      hv1[r] = o1 * (2.f / (1.f + __expf(-2.f * c1)) - 1.f);  cn1[r] = c1;
    }

    if (t == NSTEP - 1) {
      if (lr < 4) {
        #pragma unroll
        for (int r = 0; r < 4; ++r) {
          int R = w * 16 + lk * 4 + r;
          int C = jc * 8 + lr;
          out[(size_t)R * 1024 + C]              = hv0[r];
          out[65536 + (size_t)R * 1024 + C]      = hv0[r];
          out[131072 + (size_t)R * 1024 + C]     = cn0[r];
          out[(size_t)R * 1024 + C + 4]          = hv1[r];
          out[65536 + (size_t)R * 1024 + C + 4]  = hv1[r];
          out[131072 + (size_t)R * 1024 + C + 4] = cn1[r];
        }
      }
    } else {
      // pack wave's 16x8 h tile (same-wave LDS order; no barrier)
      if (lr < 4) {
        #pragma unroll
        for (int r = 0; r < 4; ++r) {
          hx[w][lk * 4 + r][lr]     = f2bf(hv0[r]);
          hx[w][lk * 4 + r][lr + 4] = f2bf(hv1[r]);
        }
      }
      if (l < 16) {   // row l: 16B contiguous -> 2 agent-scope u64 stores
        const u64* s = (const u64*)(&hx[w][l][0]);
        u64* hw = (u64*)(H + (size_t)(t + 1) * 65536
                           + (size_t)(w * 16 + l) * 1024 + jc * 8);
        AS(hw, s[0]); AS(hw + 1, s[1]);
      }
      // this wave's h stores reach the coherence point, then publish its flag
      asm volatile("s_waitcnt vmcnt(0)" ::: "memory");
      if (l == 0) AS(F + (jc * 4 + w) * 32, t + 1);
      // prefetch A1 for t+1 (fills under next step's flag wait + x-proj)
      {
        const u16* apre = A1 + ((size_t)(t + 1) * 64 + arow) * 512 + lk * 8;
        #pragma unroll
        for (int kk = 0; kk < 16; ++kk) ax[kk] = *(const bf16x8*)(apre + kk * 32);
      }
    }
  }
#undef WAITV
#undef LD8
#undef MMX
#undef MMH
}

extern "C" void kernel_launch(void* const* d_in, const int* in_sizes, int n_in,
                              void* d_out, int out_size, void* d_ws, size_t ws_size,
                              hipStream_t stream) {
  const int*   sent = (const int*)d_in[0];
  const float* emb  = (const float*)d_in[1];
  const float* w_ih = (const float*)d_in[2];
  const float* w_hh = (const float*)d_in[3];
  const float* b_ih = (const float*)d_in[4];
  const float* b_hh = (const float*)d_in[5];
  float* out = (float*)d_out;

  // A1 32Mi | H 512 x 128Ki = 64Mi | F 64Ki  (~96.1 MiB; proven available)
  char* ws = (char*)d_ws;
  u16* A1 = (u16*)ws;
  u16* H  = (u16*)(ws + 33554432);
  int* F  = (int*)(ws + 33554432 + 67108864);

  prep_kernel<<<256, 256, 0, stream>>>((u64*)H, F);
  gather_kernel<<<8192, 256, 0, stream>>>(sent, emb, A1);

  (void)hipFuncSetAttribute((const void*)lstm_kernel,
                            hipFuncAttributeMaxDynamicSharedMemorySize, WLDS_BYTES);

  void* args[] = { (void*)&A1, (void*)&w_ih, (void*)&w_hh,
                   (void*)&b_ih, (void*)&b_hh, (void*)&H, (void*)&out, (void*)&F };
  hipError_t err = hipLaunchCooperativeKernel((void*)lstm_kernel, dim3(128), dim3(256),
                                              args, WLDS_BYTES, stream);
  if (err != hipSuccess) {
    // dataflow kernel needs co-residency only; 128 WGs at 1 block/CU trivially fit
    lstm_kernel<<<dim3(128), dim3(256), WLDS_BYTES, stream>>>(A1, w_ih, w_hh,
                                                              b_ih, b_hh, H, out, F);
  }
}

// Round 21
// 4695.047 us; speedup vs baseline: 1.7526x; 1.4782x over previous
//
#include <hip/hip_runtime.h>

typedef __bf16 bf16x8 __attribute__((ext_vector_type(8)));
typedef float f32x4 __attribute__((ext_vector_type(4)));
typedef unsigned short u16;
typedef unsigned long long u64;

#define NSTEP 512

#define AL(p)   __hip_atomic_load((p), __ATOMIC_RELAXED, __HIP_MEMORY_SCOPE_AGENT)
#define AS(p,v) __hip_atomic_store((p), (v), __ATOMIC_RELAXED, __HIP_MEMORY_SCOPE_AGENT)

__device__ __forceinline__ u16 f2bf(float f) {
  union { float f; unsigned u; } x; x.f = f;
  return (u16)((x.u + 0x7fffu + ((x.u >> 16) & 1u)) >> 16);
}

// zero h buffer 0 + 256 per-WG epoch flags
__global__ void prep_kernel(u64* __restrict__ H0, int* __restrict__ F) {
  int i = blockIdx.x * blockDim.x + threadIdx.x;
  if (i < 16384) AS(H0 + i, 0ULL);
  if (i < 8192) AS(&F[i], 0);
}

// A1[t*64+b][512] bf16 embedding gather
__global__ void gather_kernel(const int* __restrict__ sent, const float* __restrict__ emb,
                              u16* __restrict__ A1) {
  int row = blockIdx.x * 4 + (threadIdx.x >> 6);   // t*64+b
  int lane = threadIdx.x & 63;
  int t = row >> 6, b = row & 63;
  int idx = sent[b * 512 + t];
  const float* src = emb + (size_t)idx * 512 + lane * 8;
  u16* dst = A1 + (size_t)row * 512 + lane * 8;
  #pragma unroll
  for (int k = 0; k < 8; ++k) dst[k] = f2bf(src[k]);
}

// 256 WGs x 256 thr. WG j owns h cols [j*4,j*4+4), gates packed rb = g*4+nn = lr.
// Weights in padded LDS. h: per-step FRESH buffers — producers store sc1,
// consumers read cached after flag detect (r12/r15-proven). No grid barrier.
// NEW (r21): ONE epoch flag per producer WG (all-waves-acked via syncthreads);
// consumer wave 0 polls globally and publishes detection to LDS ready[c];
// waves 1-3 spin on LDS — far-fabric poll transactions cut ~16x.
__global__ void __launch_bounds__(256, 2)
lstm_kernel(const u16* __restrict__ A1,
            const float* __restrict__ wih, const float* __restrict__ whh,
            const float* __restrict__ bih, const float* __restrict__ bhh,
            u16* __restrict__ H, float* __restrict__ out, int* __restrict__ F) {
  __shared__ u16 wlds[48 * 16 * 36];        // 55296 B, stride-36 pad
  __shared__ alignas(8) u16 hx[4][16][4];   // per-wave h-store packing bounce
  __shared__ int ready[4];                  // wave0 -> waves 1-3 detection relay

  const int j   = blockIdx.x;
  const int tid = threadIdx.x;
  const int w   = tid >> 6;            // wave = batch tile 0..3
  const int l   = tid & 63;
  const int lr  = l & 15, lk = l >> 4;
  const int g   = lr >> 2, nn = lr & 3;
  const int wrow = g * 1024 + j * 4 + nn;

  if (tid < 4) ready[tid] = 0;

  // ---- stage ALL weights fp32->bf16 into padded LDS (once) ----
  for (int task = tid; task < 3072; task += 256) {
    int kk = task >> 6;                 // K chunk of 32 (0..47)
    int rem = task & 63;
    int rb = rem >> 2, q = rem & 3;
    int row = (rb >> 2) * 1024 + j * 4 + (rb & 3);
    const float* src = (kk < 16) ? (wih + (size_t)row * 512 + kk * 32 + q * 8)
                                 : (whh + (size_t)row * 1024 + (kk - 16) * 32 + q * 8);
    u16* dst = wlds + (kk * 16 + rb) * 36 + q * 8;
    #pragma unroll
    for (int e = 0; e < 8; ++e) dst[e] = f2bf(src[e]);
  }
  __syncthreads();

  const float bias = bih[wrow] + bhh[wrow];
  const float sca = (g == 2) ? 2.f : 1.f;   // tanh-as-sigmoid scaling
  const float bd  = (g == 2) ? -1.f : 0.f;
  const int arow = w * 16 + lr;             // batch row for A fragments
  const u16* bx = wlds + lr * 36 + lk * 8;  // + kk*576 per K chunk

  float cst[4] = {0.f, 0.f, 0.f, 0.f};

  // prefetch A1 fragments for t=0
  bf16x8 ax[16];
  {
    const u16* apre = A1 + (size_t)arow * 512 + lk * 8;
    #pragma unroll
    for (int kk = 0; kk < 16; ++kk) ax[kk] = *(const bf16x8*)(apre + kk * 32);
  }

  union AF { bf16x8 v; u64 q[2]; };

  // WG-level flag of producer WG p at F[p*32]; chunk c covers producers c*64..+64.
  // Wave 0: global poll + LDS publish. Waves 1-3: LDS spin (no fabric traffic).
#define WAITC(c)                                                            \
  { if (w == 0) {                                                           \
      const int* fp = F + ((c) * 64 + l) * 32;                              \
      int vv = AL(fp);                                                      \
      while (vv < t) { __builtin_amdgcn_s_sleep(1); vv = AL(fp); }          \
      if (l == 0) *(volatile int*)&ready[c] = t;                            \
    } else {                                                                \
      while (*(volatile int*)&ready[c] < t) __builtin_amdgcn_s_sleep(1);    \
    } }
#define LD8(BUF, CH)                                                        \
  { _Pragma("unroll")                                                       \
    for (int r = 0; r < 8; ++r)                                             \
      BUF[r].v = *(const bf16x8*)(hp + (CH) * 256 + r * 32); }
#define MM8(ACC, BUF, W0)                                                   \
  { _Pragma("unroll")                                                       \
    for (int r = 0; r < 8; ++r) {                                           \
      bf16x8 b = *(const bf16x8*)(bx + ((W0) + r) * 576);                   \
      ACC = __builtin_amdgcn_mfma_f32_16x16x32_bf16(BUF[r].v, b, ACC, 0, 0, 0); \
    } }

  #pragma unroll 1
  for (int t = 0; t < NSTEP; ++t) {
    AF ha[8], hb[8];
    const u16* hp = H + (size_t)t * 65536 + (size_t)arow * 1024 + lk * 8;
    // x-proj first half: covers the publish->detect window
    f32x4 acx = { bias, bias, bias, bias };
    #pragma unroll
    for (int kk = 0; kk < 8; ++kk) {
      bf16x8 b = *(const bf16x8*)(bx + kk * 576);
      acx = __builtin_amdgcn_mfma_f32_16x16x32_bf16(ax[kk], b, acx, 0, 0, 0);
    }
    // detect + issue chunk 0/1 fills ASAP
    WAITC(0);
    LD8(ha, 0);
    WAITC(1);
    LD8(hb, 1);
    // x-proj second half covers the ha/hb fills
    #pragma unroll
    for (int kk = 8; kk < 16; ++kk) {
      bf16x8 b = *(const bf16x8*)(bx + kk * 576);
      acx = __builtin_amdgcn_mfma_f32_16x16x32_bf16(ax[kk], b, acx, 0, 0, 0);
    }
    // h-projection: 2 independent chains, waits woven in
    f32x4 ac1 = { 0.f, 0.f, 0.f, 0.f };
    f32x4 ac2 = { 0.f, 0.f, 0.f, 0.f };
    MM8(ac1, ha, 16);
    WAITC(2);
    LD8(ha, 2);
    MM8(ac2, hb, 24);
    WAITC(3);
    LD8(hb, 3);
    MM8(ac1, ha, 32);
    MM8(ac2, hb, 40);

    // activations + state update; lanes lr<4 own (rows lk*4+r, col lr)
    float hv4[4], cn4[4];
    #pragma unroll
    for (int r = 0; r < 4; ++r) {
      float xv = acx[r] + ac1[r] + ac2[r];
      float act = sca / (1.f + __expf(-sca * xv)) + bd;  // sigmoid / tanh
      float gg = __shfl_xor(act, 8);
      float ff = __shfl_xor(act, 4);
      float oo = __shfl_xor(act, 12);
      float cn = ff * cst[r] + act * gg;   // act = i at lanes lr<4
      cst[r] = cn;
      float tc = 2.f / (1.f + __expf(-2.f * cn)) - 1.f;
      hv4[r] = oo * tc;
      cn4[r] = cn;
    }

    if (t == NSTEP - 1) {
      if (lr < 4) {
        #pragma unroll
        for (int r = 0; r < 4; ++r) {
          int R = w * 16 + lk * 4 + r;
          out[(size_t)R * 1024 + j * 4 + lr]          = hv4[r];
          out[65536 + (size_t)R * 1024 + j * 4 + lr]  = hv4[r];
          out[131072 + (size_t)R * 1024 + j * 4 + lr] = cn4[r];
        }
      }
    } else {
      // pack wave's 16x4 h tile (same-wave LDS order)
      if (lr < 4) {
        #pragma unroll
        for (int r = 0; r < 4; ++r) hx[w][lk * 4 + r][lr] = f2bf(hv4[r]);
      }
      if (l < 16) {
        u64 pk = *(const u64*)(&hx[w][l][0]);
        u16* hw = H + (size_t)(t + 1) * 65536 + (size_t)(w * 16 + l) * 1024 + j * 4;
        AS((u64*)hw, pk);
      }
      // each wave's h stores reach the coherence point...
      asm volatile("s_waitcnt vmcnt(0)" ::: "memory");
      __syncthreads();               // ...all 4 waves acked ->
      if (tid == 0) AS(F + j * 32, t + 1);   // ONE WG-level epoch flag
      // prefetch A1 for t+1 (fills under next step's flag wait + x-proj)
      {
        const u16* apre = A1 + ((size_t)(t + 1) * 64 + arow) * 512 + lk * 8;
        #pragma unroll
        for (int kk = 0; kk < 16; ++kk) ax[kk] = *(const bf16x8*)(apre + kk * 32);
      }
    }
  }
#undef WAITC
#undef LD8
#undef MM8
}

extern "C" void kernel_launch(void* const* d_in, const int* in_sizes, int n_in,
                              void* d_out, int out_size, void* d_ws, size_t ws_size,
                              hipStream_t stream) {
  const int*   sent = (const int*)d_in[0];
  const float* emb  = (const float*)d_in[1];
  const float* w_ih = (const float*)d_in[2];
  const float* w_hh = (const float*)d_in[3];
  const float* b_ih = (const float*)d_in[4];
  const float* b_hh = (const float*)d_in[5];
  float* out = (float*)d_out;

  // A1 32Mi | H 512 x 128Ki = 64Mi | F 32Ki  (~96.1 MiB; proven available)
  char* ws = (char*)d_ws;
  u16* A1 = (u16*)ws;
  u16* H  = (u16*)(ws + 33554432);
  int* F  = (int*)(ws + 33554432 + 67108864);

  prep_kernel<<<256, 256, 0, stream>>>((u64*)H, F);
  gather_kernel<<<8192, 256, 0, stream>>>(sent, emb, A1);

  void* args[] = { (void*)&A1, (void*)&w_ih, (void*)&w_hh,
                   (void*)&b_ih, (void*)&b_hh, (void*)&H, (void*)&out, (void*)&F };
  hipError_t err = hipLaunchCooperativeKernel((void*)lstm_kernel, dim3(256), dim3(256),
                                              args, 0, stream);
  if (err != hipSuccess) {
    // dataflow kernel needs co-residency only; 2-blocks/CU envelope on 256 CUs
    lstm_kernel<<<dim3(256), dim3(256), 0, stream>>>(A1, w_ih, w_hh, b_ih, b_hh,
                                                     H, out, F);
  }
}